// Round 5
// baseline (1892.075 us; speedup 1.0000x reference)
//
#include <hip/hip_runtime.h>
#include <hip/hip_cooperative_groups.h>
#include <math.h>

namespace cg = cooperative_groups;

#define DD 2048
#define NH 16
#define HDIM 128
#define NK 8192
#define NFFN 8192
#define NHID 32
#define EPSV 1e-5f

typedef __attribute__((ext_vector_type(8))) short bf16x8;
typedef __attribute__((ext_vector_type(4))) float f32x4;

// ---- workspace layout (float offsets) ----
static const size_t W_ST  = 0;                     // state [2048]
static const size_t W_AC  = 2048;                  // acc   [2048]
static const size_t W_SC  = 4096;                  // scalars (pad 64)
static const size_t W_Q   = 4160;                  // q [2048]
static const size_t W_T   = 6208;                  // t fp32 [16][2048] (tier B)
static const size_t W_TB  = 38976;                 // t bf16 [16][2048] = 16384 floats
static const size_t W_PS  = 55360;                 // part_s [8][16][8192]
static const size_t W_P   = 1103936;               // p fp32 (tier B)
static const size_t W_PB  = 1235008;               // p bf16 [16][8192] = 65536 floats
static const size_t W_U   = 1300544;               // u [16][2048] (tier B)
static const size_t W_O   = 1333312;
static const size_t W_CR  = 1335360;
static const size_t W_S1  = 1337408;
static const size_t W_V   = 1339456;
static const size_t W_SA  = 1341504;
static const size_t W_S2  = 1343552;
static const size_t W_H1  = 1345600;               // [8192]
static const size_t W_F2  = 1353792;
static const size_t W_NS  = 1355840;
static const size_t W_PUA = 1357888;               // u parts [16][16][2048]
static const size_t W_PUB = 1882176;               // tier B u parts (overlaid by WMB in tier A)
static const size_t W_WMB = 1882176;               // wm bf16 [8192][2048]
static const size_t W_WMT = 10270784;              // wm^T bf16 [2048][8192]
static const size_t W_ENDA  = 18659392;            // tier A end (~74.6 MB)
static const size_t W_ENDB  = 6076480;

__device__ __forceinline__ float gelu_exact(float x) {
  return 0.5f * x * (1.0f + erff(x * 0.70710678118654752f));
}
__device__ __forceinline__ unsigned short f2bf(float x) {  // RNE
  unsigned u = __float_as_uint(x);
  u += 0x7FFFu + ((u >> 16) & 1u);
  return (unsigned short)(u >> 16);
}

// wave-per-row dot; x may be global or LDS (generic)
__device__ __forceinline__ float wave_dot(const float* __restrict__ w, const float* x, int C) {
  int lane = threadIdx.x & 63;
  float acc = 0.f;
  for (int c = lane * 4; c < C; c += 256) {
    float4 wv = *reinterpret_cast<const float4*>(w + c);
    float4 xx = *reinterpret_cast<const float4*>(x + c);
    acc += wv.x * xx.x + wv.y * xx.y + wv.z * xx.z + wv.w * xx.w;
  }
#pragma unroll
  for (int off = 32; off; off >>= 1) acc += __shfl_xor(acc, off, 64);
  return acc;
}

// per-block redundant LayerNorm: o = LN(x1+x2)*g+b, o in LDS (256 threads)
__device__ void block_ln(const float* x1, const float* x2,
                         const float* __restrict__ g, const float* __restrict__ be,
                         float* o, float* red) {
  int tid = threadIdx.x;
  float loc[8]; float s = 0.f;
#pragma unroll
  for (int j = 0; j < 8; ++j) { int i = tid * 8 + j; float v = x1[i] + x2[i]; loc[j] = v; s += v; }
#pragma unroll
  for (int off = 32; off; off >>= 1) s += __shfl_xor(s, off, 64);
  __syncthreads();
  if ((tid & 63) == 0) red[tid >> 6] = s;
  __syncthreads();
  float m = (red[0] + red[1] + red[2] + red[3]) * (1.f / 2048.f);
  s = 0.f;
#pragma unroll
  for (int j = 0; j < 8; ++j) { float d = loc[j] - m; s += d * d; }
#pragma unroll
  for (int off = 32; off; off >>= 1) s += __shfl_xor(s, off, 64);
  __syncthreads();
  if ((tid & 63) == 0) red[tid >> 6] = s;
  __syncthreads();
  float inv = 1.f / sqrtf((red[0] + red[1] + red[2] + red[3]) * (1.f / 2048.f) + EPSV);
#pragma unroll
  for (int j = 0; j < 8; ++j) { int i = tid * 8 + j; o[i] = (loc[j] - m) * inv * g[i] + be[i]; }
  __syncthreads();
}

// one-time: wm fp32 -> wmb (row-major bf16) + wmbT (transposed bf16)
__global__ void prep_wm(const float* __restrict__ wm, unsigned short* __restrict__ wmb,
                        unsigned short* __restrict__ wmbT) {
  __shared__ unsigned short tile[64][72];
  int bk = blockIdx.x & 127, bc = blockIdx.x >> 7;
  int k0 = bk * 64, c0 = bc * 64;
  int tx = threadIdx.x & 15, ty = threadIdx.x >> 4;
#pragma unroll
  for (int rr = 0; rr < 4; ++rr) {
    int r = ty + rr * 16;
    float4 v = *reinterpret_cast<const float4*>(wm + (size_t)(k0 + r) * DD + c0 + tx * 4);
    ushort4 u4;
    u4.x = f2bf(v.x); u4.y = f2bf(v.y); u4.z = f2bf(v.z); u4.w = f2bf(v.w);
    *reinterpret_cast<ushort4*>(wmb + (size_t)(k0 + r) * DD + c0 + tx * 4) = u4;
    tile[tx * 4 + 0][r] = u4.x; tile[tx * 4 + 1][r] = u4.y;
    tile[tx * 4 + 2][r] = u4.z; tile[tx * 4 + 3][r] = u4.w;
  }
  __syncthreads();
#pragma unroll
  for (int rr = 0; rr < 4; ++rr) {
    int c = ty + rr * 16;
    ushort4 o;
    o.x = tile[c][tx * 4]; o.y = tile[c][tx * 4 + 1];
    o.z = tile[c][tx * 4 + 2]; o.w = tile[c][tx * 4 + 3];
    *reinterpret_cast<ushort4*>(wmbT + (size_t)(c0 + c) * NK + k0 + tx * 4) = o;
  }
}

struct MegaP {
  const float *self_in_w, *self_in_b, *self_out_w, *self_out_b;
  const float *cross_in_w, *cross_in_b, *cross_out_w, *cross_out_b;
  const float *ffn_w1, *ffn_b1, *ffn_w2, *ffn_b2;
  const float *ln1_g, *ln1_b, *ln2_g, *ln2_b, *ln3_g, *ln3_b;
  const float *hw1, *hb1, *hw2, *hb2;
  const int* max_steps;
  const float* w0;
  const unsigned short *wmb, *wmt;
  float *ST, *AC, *SC, *Q;
  unsigned short *TB, *PB;
  float *PS, *PU, *O, *CR, *V, *SA, *H1, *F2, *out;
};

__global__ __launch_bounds__(256, 4) void mega_kernel(MegaP P) {
  cg::grid_group grd = cg::this_grid();
  __shared__ float sxA[2048];
  __shared__ float sxB[2048];
  __shared__ float red[8];
  const int tid = threadIdx.x, bid = blockIdx.x, nb = gridDim.x;
  const int wid = tid >> 6, lane = tid & 63;
  const int gw = bid * 4 + wid, nw = nb * 4;
  const int l15 = lane & 15, kg = lane >> 4;

  // init: state <- w0, acc <- 0, cum=0 active=1
  for (int i = bid * 256 + tid; i < DD; i += nb * 256) { P.ST[i] = P.w0[i]; P.AC[i] = 0.f; }
  if (bid == 0 && tid == 0) { P.SC[0] = 0.f; P.SC[1] = 1.f; }
  const int ms = P.max_steps[0];
  grd.sync();

  for (int s = 0; s < 5; ++s) {
    if (s >= ms) break;
    if (P.SC[1] == 0.f) break;   // uniform: single writer, ordered by grid sync

    // P1: q = Wq @ state + bq
    for (int r = gw; r < DD; r += nw) {
      float a = wave_dot(P.cross_in_w + (size_t)r * DD, P.ST, DD);
      if (lane == 0) P.Q[r] = a + P.cross_in_b[r];
    }
    grd.sync();

    // P2: t[h][c] = q_h . Wk_h[:,c]  (bf16 out)
    for (int idx = bid * 256 + tid; idx < NH * DD; idx += nb * 256) {
      int h = idx >> 11, c = idx & 2047;
      const float* wb = P.cross_in_w + (size_t)DD * DD + (size_t)(h * HDIM) * DD + c;
      const float* qh = P.Q + h * HDIM;
      float acc = 0.f;
      for (int d = 0; d < HDIM; ++d) acc += qh[d] * wb[(size_t)d * DD];
      P.TB[idx] = f2bf(acc);
    }
    grd.sync();

    // P3: scores partials (MFMA), part_s[cc][h][r]
    for (int task = gw; task < 4096; task += nw) {
      int cc = task & 7, rg = task >> 3;
      int r0 = rg * 16, c0 = cc * 256;
      const unsigned short* ap = P.wmb + (size_t)(r0 + l15) * DD + c0 + kg * 8;
      const unsigned short* bp = P.TB + (size_t)l15 * DD + c0 + kg * 8;
      f32x4 acc = {0.f, 0.f, 0.f, 0.f};
#pragma unroll
      for (int q4 = 0; q4 < 2; ++q4) {
        bf16x8 a[4], b[4];
#pragma unroll
        for (int i = 0; i < 4; ++i) {
          a[i] = *reinterpret_cast<const bf16x8*>(ap + q4 * 128 + i * 32);
          b[i] = *reinterpret_cast<const bf16x8*>(bp + q4 * 128 + i * 32);
        }
#pragma unroll
        for (int i = 0; i < 4; ++i)
          acc = __builtin_amdgcn_mfma_f32_16x16x32_bf16(a[i], b[i], acc, 0, 0, 0);
      }
      float* op = P.PS + ((size_t)cc * NH + l15) * NK + r0 + kg * 4;
#pragma unroll
      for (int r = 0; r < 4; ++r) op[r] = acc[r];
    }
    grd.sync();

    // P4: per-head softmax -> PB (bf16)
    for (int h = bid; h < NH; h += nb) {
      float v[32]; float mx = -1e30f;
      for (int j = 0; j < 32; ++j) {
        int k = tid + j * 256; float ss = 0.f;
        for (int cc = 0; cc < 8; ++cc) ss += P.PS[((size_t)cc * NH + h) * NK + k];
        ss *= 0.08838834764831845f; v[j] = ss; mx = fmaxf(mx, ss);
      }
      sxA[tid] = mx; __syncthreads();
      for (int off = 128; off; off >>= 1) { if (tid < off) sxA[tid] = fmaxf(sxA[tid], sxA[tid + off]); __syncthreads(); }
      mx = sxA[0]; __syncthreads();
      float sum = 0.f;
      for (int j = 0; j < 32; ++j) { v[j] = expf(v[j] - mx); sum += v[j]; }
      sxA[tid] = sum; __syncthreads();
      for (int off = 128; off; off >>= 1) { if (tid < off) sxA[tid] += sxA[tid + off]; __syncthreads(); }
      float inv = 1.f / sxA[0]; __syncthreads();
      for (int j = 0; j < 32; ++j) P.PB[(size_t)h * NK + tid + j * 256] = f2bf(v[j] * inv);
    }
    grd.sync();

    // P5: u partials (MFMA), part_u[kc][h][c]
    for (int task = gw; task < 2048; task += nw) {
      int ct = task & 127, kc = task >> 7;
      int c0 = ct * 16, k0 = kc * 512;
      const unsigned short* ap = P.PB + (size_t)l15 * NK + k0 + kg * 8;
      const unsigned short* bp = P.wmt + (size_t)(c0 + l15) * NK + k0 + kg * 8;
      f32x4 acc = {0.f, 0.f, 0.f, 0.f};
#pragma unroll
      for (int q4 = 0; q4 < 4; ++q4) {
        bf16x8 a[4], b[4];
#pragma unroll
        for (int i = 0; i < 4; ++i) {
          a[i] = *reinterpret_cast<const bf16x8*>(ap + q4 * 128 + i * 32);
          b[i] = *reinterpret_cast<const bf16x8*>(bp + q4 * 128 + i * 32);
        }
#pragma unroll
        for (int i = 0; i < 4; ++i)
          acc = __builtin_amdgcn_mfma_f32_16x16x32_bf16(a[i], b[i], acc, 0, 0, 0);
      }
      float* op = P.PU + ((size_t)kc * NH + kg * 4) * DD + c0 + l15;
#pragma unroll
      for (int r = 0; r < 4; ++r) op[(size_t)r * DD] = acc[r];
    }
    grd.sync();

    // P6: fuse u-reduce (LDS) + per-head Wv_cross matvec -> O ; 512 tasks (4 rows each)
    for (int task = bid; task < 512; task += nb) {
      int h = task >> 5;
#pragma unroll 2
      for (int j = 0; j < 8; ++j) {
        int c = tid * 8 + j;
        float ss = 0.f;
#pragma unroll
        for (int kc = 0; kc < 16; ++kc) ss += P.PU[((size_t)kc * NH + h) * DD + c];
        sxA[c] = ss;
      }
      __syncthreads();
      int row = h * HDIM + (task & 31) * 4 + wid;
      float a = wave_dot(P.cross_in_w + (size_t)2 * DD * DD + (size_t)row * DD, sxA, DD);
      if (lane == 0) P.O[row] = a + P.cross_in_b[2 * DD + row];
      __syncthreads();
    }
    grd.sync();

    // P7: cross = cross_out_w @ o + b
    for (int r = gw; r < DD; r += nw) {
      float a = wave_dot(P.cross_out_w + (size_t)r * DD, P.O, DD);
      if (lane == 0) P.CR[r] = a + P.cross_out_b[r];
    }
    grd.sync();

    // P8: s1 = ln1(state+cross) per-block in LDS; V = Wv_self @ s1 + bv
    block_ln(P.ST, P.CR, P.ln1_g, P.ln1_b, sxA, red);
    for (int r = gw; r < DD; r += nw) {
      float a = wave_dot(P.self_in_w + (size_t)2 * DD * DD + (size_t)r * DD, sxA, DD);
      if (lane == 0) P.V[r] = a + P.self_in_b[2 * DD + r];
    }
    grd.sync();

    // P9: sa = self_out_w @ v + b
    for (int r = gw; r < DD; r += nw) {
      float a = wave_dot(P.self_out_w + (size_t)r * DD, P.V, DD);
      if (lane == 0) P.SA[r] = a + P.self_out_b[r];
    }
    grd.sync();

    // P10: s2 = ln2(s1+sa) in LDS; H1 = gelu(ffn_w1 @ s2 + b1)
    block_ln(P.ST, P.CR, P.ln1_g, P.ln1_b, sxA, red);
    block_ln(sxA, P.SA, P.ln2_g, P.ln2_b, sxB, red);
    for (int r = gw; r < NFFN; r += nw) {
      float a = wave_dot(P.ffn_w1 + (size_t)r * DD, sxB, DD);
      if (lane == 0) P.H1[r] = gelu_exact(a + P.ffn_b1[r]);
    }
    grd.sync();

    // P11: F2 = ffn_w2 @ h + b2
    for (int r = gw; r < DD; r += nw) {
      float a = wave_dot(P.ffn_w2 + (size_t)r * NFFN, P.H1, NFFN);
      if (lane == 0) P.F2[r] = a + P.ffn_b2[r];
    }
    grd.sync();

    // P12: block 0: ns = ln3(s2+F2); halt head; ACT update
    if (bid == 0) {
      block_ln(P.ST, P.CR, P.ln1_g, P.ln1_b, sxA, red);
      block_ln(sxA, P.SA, P.ln2_g, P.ln2_b, sxB, red);
      block_ln(sxB, P.F2, P.ln3_g, P.ln3_b, sxA, red);   // sxA = ns
      int row = tid >> 3, seg = tid & 7;
      const float* wr = P.hw1 + (size_t)row * DD + seg * 256;
      const float* np = sxA + seg * 256;
      float ss = 0.f;
      for (int i = 0; i < 256; ++i) ss += wr[i] * np[i];
      sxB[row * 8 + seg] = ss;
      __syncthreads();
      if (tid < NHID) {
        float t2 = P.hb1[tid];
#pragma unroll
        for (int j = 0; j < 8; ++j) t2 += sxB[tid * 8 + j];
        sxB[256 + tid] = gelu_exact(t2);
      }
      __syncthreads();
      if (tid == 0) {
        float hs = P.hb2[0];
        for (int j = 0; j < NHID; ++j) hs += sxB[256 + j] * P.hw2[j];
        float halt = 1.f / (1.f + expf(-hs));
        float cum = P.SC[0];
        float ncum = cum + halt;
        int halts = (ncum >= 1.f - 1e-6f);
        sxB[300] = halts ? (1.f - cum) : halt;
        P.SC[0] = ncum;
        P.SC[1] = halts ? 0.f : 1.f;
      }
      __syncthreads();
      float wv2 = sxB[300];
      for (int i = tid; i < DD; i += 256) { P.AC[i] += wv2 * sxA[i]; P.ST[i] = sxA[i]; }
    }
    grd.sync();
  }

  // final: out = acc + (cum<1-1e-6 ? 1-cum : 0) * state
  float cum = P.SC[0];
  float wv2 = (cum < 1.f - 1e-6f) ? (1.f - cum) : 0.f;
  for (int i = bid * 256 + tid; i < DD; i += nb * 256) P.out[i] = P.AC[i] + wv2 * P.ST[i];
}

// ================= tier B fallback (fp32 multi-kernel, from R4) =================

__global__ void init_kernel(const float* __restrict__ w0, float* __restrict__ state,
                            float* __restrict__ acc, float* __restrict__ scal) {
  int i = blockIdx.x * 256 + threadIdx.x;
  if (i < DD) { state[i] = w0[i]; acc[i] = 0.f; }
  if (i == 0) { scal[0] = 0.f; scal[1] = 1.f; }
}

__global__ void matvec_kernel(const float* __restrict__ W, const float* __restrict__ bias,
                              const float* __restrict__ x, float* __restrict__ y,
                              int R, int C, int act, int perhead,
                              const float* __restrict__ scal, int gated) {
  if (gated && scal[1] == 0.f) return;
  int wid = threadIdx.x >> 6, lane = threadIdx.x & 63;
  int row = blockIdx.x * 4 + wid;
  if (row >= R) return;
  const float* w = W + (size_t)row * C;
  const float* xv = perhead ? (x + (size_t)(row >> 7) * C) : x;
  float acc = 0.f;
  for (int c = lane * 4; c < C; c += 256) {
    float4 wv = *reinterpret_cast<const float4*>(w + c);
    float4 xx = *reinterpret_cast<const float4*>(xv + c);
    acc += wv.x * xx.x + wv.y * xx.y + wv.z * xx.z + wv.w * xx.w;
  }
  for (int off = 32; off > 0; off >>= 1) acc += __shfl_xor(acc, off, 64);
  if (lane == 0) {
    float r = acc + bias[row];
    if (act == 1) r = gelu_exact(r);
    y[row] = r;
  }
}

__global__ void tproj_kernel(const float* __restrict__ Wk, const float* __restrict__ q,
                             float* __restrict__ t, const float* __restrict__ scal) {
  if (scal[1] == 0.f) return;
  int h = blockIdx.x >> 4, ct = blockIdx.x & 15;
  int c = ct * 128 + threadIdx.x;
  const float* wb = Wk + (size_t)(h * HDIM) * DD + c;
  const float* qh = q + h * HDIM;
  float acc = 0.f;
  for (int d = 0; d < HDIM; ++d) acc += qh[d] * wb[(size_t)d * DD];
  t[h * DD + c] = acc;
}

#define FMA16(wvv, tp)                                                       \
  {                                                                          \
    float4 t0 = tp[0], t1 = tp[1], t2 = tp[2], t3 = tp[3];                   \
    acc[0] += wvv * t0.x; acc[1] += wvv * t0.y;                              \
    acc[2] += wvv * t0.z; acc[3] += wvv * t0.w;                              \
    acc[4] += wvv * t1.x; acc[5] += wvv * t1.y;                              \
    acc[6] += wvv * t1.z; acc[7] += wvv * t1.w;                              \
    acc[8] += wvv * t2.x; acc[9] += wvv * t2.y;                              \
    acc[10] += wvv * t2.z; acc[11] += wvv * t2.w;                            \
    acc[12] += wvv * t3.x; acc[13] += wvv * t3.y;                            \
    acc[14] += wvv * t3.z; acc[15] += wvv * t3.w;                            \
  }

__global__ void scores_kernel(const float* __restrict__ wm, const float* __restrict__ t,
                              float* __restrict__ part_s, const float* __restrict__ scal) {
  if (scal[1] == 0.f) return;
  int kt = blockIdx.x >> 3, cc = blockIdx.x & 7;
  int tid = threadIdx.x;
  int k0 = kt * 128, c0 = cc * 256;
  __shared__ float wlds[128 * 33];
  __shared__ float tlds[256 * 20];
  for (int j = 0; j < 32; ++j) {
    int idx = j * 128 + tid;
    int h = idx >> 8, c = idx & 255;
    tlds[c * 20 + h] = t[(size_t)h * DD + c0 + c];
  }
  float acc[NH];
#pragma unroll
  for (int h = 0; h < NH; ++h) acc[h] = 0.f;
  for (int sl = 0; sl < 8; ++sl) {
    int cbase = c0 + sl * 32;
    __syncthreads();
    for (int p = 0; p < 8; ++p) {
      int f = p * 128 + tid;
      int r = f >> 3, fc = f & 7;
      float4 v = *reinterpret_cast<const float4*>(wm + (size_t)(k0 + r) * DD + cbase + fc * 4);
      float* d = wlds + r * 33 + fc * 4;
      d[0] = v.x; d[1] = v.y; d[2] = v.z; d[3] = v.w;
    }
    __syncthreads();
    const float* myrow = wlds + tid * 33;
#pragma unroll 4
    for (int cb = 0; cb < 32; ++cb) {
      float wvv = myrow[cb];
      const float4* tp = reinterpret_cast<const float4*>(tlds + (size_t)(sl * 32 + cb) * 20);
      FMA16(wvv, tp);
    }
  }
#pragma unroll
  for (int h = 0; h < NH; ++h)
    part_s[((size_t)cc * NH + h) * NK + k0 + tid] = acc[h];
}

__global__ void softmax_kernel(const float* __restrict__ part_s, float* __restrict__ p,
                               const float* __restrict__ scal) {
  if (scal[1] == 0.f) return;
  int h = blockIdx.x, tid = threadIdx.x;
  __shared__ float red[256];
  float v[32]; float mx = -1e30f;
  for (int j = 0; j < 32; ++j) {
    int k = tid + j * 256; float s = 0.f;
    for (int cc = 0; cc < 8; ++cc) s += part_s[((size_t)cc * NH + h) * NK + k];
    s *= 0.08838834764831845f;
    v[j] = s; mx = fmaxf(mx, s);
  }
  red[tid] = mx; __syncthreads();
  for (int off = 128; off > 0; off >>= 1) { if (tid < off) red[tid] = fmaxf(red[tid], red[tid + off]); __syncthreads(); }
  mx = red[0]; __syncthreads();
  float sum = 0.f;
  for (int j = 0; j < 32; ++j) { v[j] = expf(v[j] - mx); sum += v[j]; }
  red[tid] = sum; __syncthreads();
  for (int off = 128; off > 0; off >>= 1) { if (tid < off) red[tid] += red[tid + off]; __syncthreads(); }
  float inv = 1.f / red[0];
  for (int j = 0; j < 32; ++j) p[(size_t)h * NK + tid + j * 256] = v[j] * inv;
}

#define U1FMA(i, ph) \
  acc[i].x += w4.x * (ph); acc[i].y += w4.y * (ph); \
  acc[i].z += w4.z * (ph); acc[i].w += w4.w * (ph);

template <int KCH>
__global__ void u1_kernel(const float* __restrict__ wm, const float* __restrict__ p,
                          float* __restrict__ part_u, const float* __restrict__ scal) {
  if (scal[1] == 0.f) return;
  int kc = blockIdx.x >> 2, ct = blockIdx.x & 3;
  int tid = threadIdx.x;
  int k0 = kc * KCH;
  int c = ct * 512 + tid * 4;
  __shared__ float plds[KCH * 16];
  for (int j = 0; j < KCH * 16 / 128; ++j) {
    int idx = j * 128 + tid;
    int h = idx / KCH, k = idx % KCH;
    plds[k * 16 + h] = p[(size_t)h * NK + k0 + k];
  }
  __syncthreads();
  float4 acc[NH];
#pragma unroll
  for (int h = 0; h < NH; ++h) acc[h] = make_float4(0.f, 0.f, 0.f, 0.f);
#pragma unroll 2
  for (int k = 0; k < KCH; ++k) {
    float4 w4 = *reinterpret_cast<const float4*>(wm + (size_t)(k0 + k) * DD + c);
    const float4* pp = reinterpret_cast<const float4*>(plds + k * 16);
    float4 p0 = pp[0], p1 = pp[1], p2 = pp[2], p3 = pp[3];
    U1FMA(0, p0.x)  U1FMA(1, p0.y)  U1FMA(2, p0.z)  U1FMA(3, p0.w)
    U1FMA(4, p1.x)  U1FMA(5, p1.y)  U1FMA(6, p1.z)  U1FMA(7, p1.w)
    U1FMA(8, p2.x)  U1FMA(9, p2.y)  U1FMA(10, p2.z) U1FMA(11, p2.w)
    U1FMA(12, p3.x) U1FMA(13, p3.y) U1FMA(14, p3.z) U1FMA(15, p3.w)
  }
#pragma unroll
  for (int h = 0; h < NH; ++h)
    *reinterpret_cast<float4*>(part_u + ((size_t)kc * NH + h) * DD + c) = acc[h];
}

__global__ void u2_kernel(const float* __restrict__ part_u, float* __restrict__ u,
                          const float* __restrict__ scal, int nkc) {
  if (scal[1] == 0.f) return;
  int i = blockIdx.x * 256 + threadIdx.x;
  float s = 0.f;
  for (int kc = 0; kc < nkc; ++kc) s += part_u[(size_t)kc * NH * DD + i];
  u[i] = s;
}

__global__ void ln_kernel(const float* __restrict__ a, const float* __restrict__ r,
                          const float* __restrict__ g, const float* __restrict__ beta,
                          float* __restrict__ out, const float* __restrict__ scal) {
  if (scal[1] == 0.f) return;
  __shared__ float red[256];
  __shared__ float mv[2];
  int tid = threadIdx.x;
  float x[8]; float s = 0.f;
  for (int j = 0; j < 8; ++j) { int i = tid * 8 + j; x[j] = a[i] + r[i]; s += x[j]; }
  red[tid] = s; __syncthreads();
  for (int off = 128; off > 0; off >>= 1) { if (tid < off) red[tid] += red[tid + off]; __syncthreads(); }
  if (tid == 0) mv[0] = red[0] * (1.f / DD);
  __syncthreads();
  float m = mv[0]; s = 0.f;
  for (int j = 0; j < 8; ++j) { float d = x[j] - m; s += d * d; }
  red[tid] = s; __syncthreads();
  for (int off = 128; off > 0; off >>= 1) { if (tid < off) red[tid] += red[tid + off]; __syncthreads(); }
  if (tid == 0) mv[1] = 1.f / sqrtf(red[0] * (1.f / DD) + EPSV);
  __syncthreads();
  float inv = mv[1];
  for (int j = 0; j < 8; ++j) { int i = tid * 8 + j; out[i] = (x[j] - m) * inv * g[i] + beta[i]; }
}

__global__ void act_kernel(const float* __restrict__ hw1, const float* __restrict__ hb1,
                           const float* __restrict__ hw2, const float* __restrict__ hb2,
                           const float* __restrict__ ns, float* __restrict__ state,
                           float* __restrict__ acc, float* __restrict__ scal,
                           const int* __restrict__ max_steps, int step) {
  if (step >= max_steps[0]) return;
  if (scal[1] == 0.f) return;
  __shared__ float red[NHID][9];
  __shared__ float hh[NHID];
  __shared__ float wbc;
  int tid = threadIdx.x;
  int row = tid >> 3, seg = tid & 7;
  const float* wr = hw1 + (size_t)row * DD + seg * 256;
  const float* nsp = ns + seg * 256;
  float s = 0.f;
  for (int i = 0; i < 256; ++i) s += wr[i] * nsp[i];
  red[row][seg] = s; __syncthreads();
  if (tid < NHID) {
    float t = hb1[tid];
    for (int j = 0; j < 8; ++j) t += red[tid][j];
    hh[tid] = gelu_exact(t);
  }
  __syncthreads();
  if (tid == 0) {
    float hs = hb2[0];
    for (int j = 0; j < NHID; ++j) hs += hh[j] * hw2[j];
    float halt = 1.f / (1.f + expf(-hs));
    float cum = scal[0];
    float ncum = cum + halt;
    int halts = (ncum >= 1.f - 1e-6f);
    wbc = halts ? (1.f - cum) : halt;
    scal[0] = ncum;
    scal[1] = halts ? 0.f : 1.f;
  }
  __syncthreads();
  float w = wbc;
  for (int i = tid; i < DD; i += 256) { acc[i] += w * ns[i]; state[i] = ns[i]; }
}

__global__ void final_kernel(const float* __restrict__ state, const float* __restrict__ acc,
                             const float* __restrict__ scal, float* __restrict__ out) {
  float cum = scal[0];
  float w = (cum < 1.f - 1e-6f) ? (1.f - cum) : 0.f;
  int i = blockIdx.x * 256 + threadIdx.x;
  if (i < DD) out[i] = acc[i] + w * state[i];
}

extern "C" void kernel_launch(void* const* d_in, const int* in_sizes, int n_in,
                              void* d_out, int out_size, void* d_ws, size_t ws_size,
                              hipStream_t stream) {
  const float* workspace   = (const float*)d_in[0];
  const float* wm          = (const float*)d_in[1];
  const float* self_in_w   = (const float*)d_in[2];
  const float* self_in_b   = (const float*)d_in[3];
  const float* self_out_w  = (const float*)d_in[4];
  const float* self_out_b  = (const float*)d_in[5];
  const float* cross_in_w  = (const float*)d_in[6];
  const float* cross_in_b  = (const float*)d_in[7];
  const float* cross_out_w = (const float*)d_in[8];
  const float* cross_out_b = (const float*)d_in[9];
  const float* ffn_w1      = (const float*)d_in[10];
  const float* ffn_b1      = (const float*)d_in[11];
  const float* ffn_w2      = (const float*)d_in[12];
  const float* ffn_b2      = (const float*)d_in[13];
  const float* ln1_g = (const float*)d_in[14];
  const float* ln1_b = (const float*)d_in[15];
  const float* ln2_g = (const float*)d_in[16];
  const float* ln2_b = (const float*)d_in[17];
  const float* ln3_g = (const float*)d_in[18];
  const float* ln3_b = (const float*)d_in[19];
  const float* halt_w1 = (const float*)d_in[20];
  const float* halt_b1 = (const float*)d_in[21];
  const float* halt_w2 = (const float*)d_in[22];
  const float* halt_b2 = (const float*)d_in[23];
  const int*   max_steps = (const int*)d_in[24];

  float* ws = (float*)d_ws;
  float* out = (float*)d_out;

  unsigned short* TB  = (unsigned short*)(ws + W_TB);
  unsigned short* PB  = (unsigned short*)(ws + W_PB);
  unsigned short* WMB = (unsigned short*)(ws + W_WMB);
  unsigned short* WMT = (unsigned short*)(ws + W_WMT);

  const bool tierA = W_ENDA * sizeof(float) <= ws_size;

  if (tierA) {
    prep_wm<<<4096, 256, 0, stream>>>(wm, WMB, WMT);

    MegaP p;
    p.self_in_w = self_in_w;   p.self_in_b = self_in_b;
    p.self_out_w = self_out_w; p.self_out_b = self_out_b;
    p.cross_in_w = cross_in_w; p.cross_in_b = cross_in_b;
    p.cross_out_w = cross_out_w; p.cross_out_b = cross_out_b;
    p.ffn_w1 = ffn_w1; p.ffn_b1 = ffn_b1; p.ffn_w2 = ffn_w2; p.ffn_b2 = ffn_b2;
    p.ln1_g = ln1_g; p.ln1_b = ln1_b; p.ln2_g = ln2_g; p.ln2_b = ln2_b;
    p.ln3_g = ln3_g; p.ln3_b = ln3_b;
    p.hw1 = halt_w1; p.hb1 = halt_b1; p.hw2 = halt_w2; p.hb2 = halt_b2;
    p.max_steps = max_steps; p.w0 = workspace;
    p.wmb = WMB; p.wmt = WMT;
    p.ST = ws + W_ST; p.AC = ws + W_AC; p.SC = ws + W_SC; p.Q = ws + W_Q;
    p.TB = TB; p.PB = PB;
    p.PS = ws + W_PS; p.PU = ws + W_PUA; p.O = ws + W_O; p.CR = ws + W_CR;
    p.V = ws + W_V; p.SA = ws + W_SA; p.H1 = ws + W_H1; p.F2 = ws + W_F2;
    p.out = out;

    int G = 1024;
    int occ = 0;
    if (hipOccupancyMaxActiveBlocksPerMultiprocessor(&occ, (const void*)mega_kernel, 256, 0)
            == hipSuccess && occ > 0) {
      int dev = 0;
      hipGetDevice(&dev);
      hipDeviceProp_t prop;
      if (hipGetDeviceProperties(&prop, dev) == hipSuccess)
        G = occ * prop.multiProcessorCount;
    }
    if (G > 1024) G = 1024;
    if (G < 64) G = 64;

    void* args[] = {(void*)&p};
    hipLaunchCooperativeKernel((const void*)mega_kernel, dim3(G), dim3(256), args, 0, stream);
  } else {
    float* ST = ws + W_ST;  float* AC = ws + W_AC;  float* SC = ws + W_SC;
    float* Q_ = ws + W_Q;   float* T_ = ws + W_T;   float* PS = ws + W_PS;
    float* P_ = ws + W_P;   float* U_ = ws + W_U;   float* O_ = ws + W_O;
    float* CR = ws + W_CR;  float* S1 = ws + W_S1;  float* V_ = ws + W_V;
    float* SA = ws + W_SA;  float* S2 = ws + W_S2;  float* H1 = ws + W_H1;
    float* F2 = ws + W_F2;  float* NS = ws + W_NS;  float* PUB = ws + W_PUB;
    const bool bigB = W_ENDB * sizeof(float) <= ws_size;

    init_kernel<<<8, 256, 0, stream>>>(workspace, ST, AC, SC);
    for (int s = 0; s < 5; ++s) {
      matvec_kernel<<<512, 256, 0, stream>>>(cross_in_w, cross_in_b, ST, Q_, DD, DD, 0, 0, SC, 1);
      tproj_kernel<<<256, 128, 0, stream>>>(cross_in_w + (size_t)DD * DD, Q_, T_, SC);
      scores_kernel<<<512, 128, 0, stream>>>(wm, T_, PS, SC);
      softmax_kernel<<<16, 256, 0, stream>>>(PS, P_, SC);
      if (bigB) u1_kernel<64><<<512, 128, 0, stream>>>(wm, P_, PUB, SC);
      else      u1_kernel<256><<<128, 128, 0, stream>>>(wm, P_, PUB, SC);
      u2_kernel<<<128, 256, 0, stream>>>(PUB, U_, SC, bigB ? 128 : 32);
      matvec_kernel<<<512, 256, 0, stream>>>(cross_in_w + (size_t)2 * DD * DD, cross_in_b + 2 * DD,
                                             U_, O_, DD, DD, 0, 1, SC, 1);
      matvec_kernel<<<512, 256, 0, stream>>>(cross_out_w, cross_out_b, O_, CR, DD, DD, 0, 0, SC, 1);
      ln_kernel<<<1, 256, 0, stream>>>(ST, CR, ln1_g, ln1_b, S1, SC);
      matvec_kernel<<<512, 256, 0, stream>>>(self_in_w + (size_t)2 * DD * DD, self_in_b + 2 * DD,
                                             S1, V_, DD, DD, 0, 0, SC, 1);
      matvec_kernel<<<512, 256, 0, stream>>>(self_out_w, self_out_b, V_, SA, DD, DD, 0, 0, SC, 1);
      ln_kernel<<<1, 256, 0, stream>>>(S1, SA, ln2_g, ln2_b, S2, SC);
      matvec_kernel<<<2048, 256, 0, stream>>>(ffn_w1, ffn_b1, S2, H1, NFFN, DD, 1, 0, SC, 1);
      matvec_kernel<<<512, 256, 0, stream>>>(ffn_w2, ffn_b2, H1, F2, DD, NFFN, 0, 0, SC, 1);
      ln_kernel<<<1, 256, 0, stream>>>(S2, F2, ln3_g, ln3_b, NS, SC);
      act_kernel<<<1, 256, 0, stream>>>(halt_w1, halt_b1, halt_w2, halt_b2, NS, ST, AC, SC,
                                        max_steps, s);
    }
    final_kernel<<<8, 256, 0, stream>>>(ST, AC, SC, out);
  }
}

// Round 6
// 368.088 us; speedup vs baseline: 5.1403x; 5.1403x over previous
//
#include <hip/hip_runtime.h>
#include <math.h>

#define DD 2048
#define NH 16
#define HDIM 128
#define NK 8192
#define NFFN 8192
#define NHID 32
#define EPSV 1e-5f

typedef __attribute__((ext_vector_type(8))) short bf16x8;
typedef __attribute__((ext_vector_type(4))) float f32x4;

// ---- workspace layout (float offsets) ----
static const size_t W_ST  = 0;                     // state [2048]
static const size_t W_AC  = 2048;                  // acc   [2048]
static const size_t W_SC  = 4096;                  // scalars (pad 64)
static const size_t W_Q   = 4160;                  // q [2048]
static const size_t W_T   = 6208;                  // t fp32 [16][2048] (tier B)
static const size_t W_TB  = 38976;                 // t bf16 [16][2048] = 16384 floats
static const size_t W_PS  = 55360;                 // part_s [8][16][8192]
static const size_t W_P   = 1103936;               // p fp32 (tier B)
static const size_t W_PB  = 1235008;               // p bf16 [16][8192] = 65536 floats
static const size_t W_U   = 1300544;               // u [16][2048] (tier B)
static const size_t W_O   = 1333312;
static const size_t W_CR  = 1335360;
static const size_t W_S1  = 1337408;               // (tier B)
static const size_t W_V   = 1339456;
static const size_t W_SA  = 1341504;
static const size_t W_S2  = 1343552;               // (tier B)
static const size_t W_H1  = 1345600;               // [8192]
static const size_t W_F2  = 1353792;
static const size_t W_NS  = 1355840;               // (tier B)
static const size_t W_PUA = 1357888;               // u parts [16][16][2048]
static const size_t W_PUB = 1882176;               // tier B u parts (overlaid by WMB in tier A)
static const size_t W_WMB = 1882176;               // wm bf16 [8192][2048]
static const size_t W_WMT = 10270784;              // wm^T bf16 [2048][8192]
static const size_t W_ENDA  = 18659392;            // tier A end (~74.6 MB)
static const size_t W_ENDB  = 6076480;

__device__ __forceinline__ float gelu_exact(float x) {
  return 0.5f * x * (1.0f + erff(x * 0.70710678118654752f));
}
__device__ __forceinline__ unsigned short f2bf(float x) {  // RNE
  unsigned u = __float_as_uint(x);
  u += 0x7FFFu + ((u >> 16) & 1u);
  return (unsigned short)(u >> 16);
}

// wave-per-row dot; x may be global or LDS (generic pointer)
__device__ __forceinline__ float wave_dot(const float* __restrict__ w, const float* x, int C) {
  int lane = threadIdx.x & 63;
  float acc = 0.f;
  for (int c = lane * 4; c < C; c += 256) {
    float4 wv = *reinterpret_cast<const float4*>(w + c);
    float4 xx = *reinterpret_cast<const float4*>(x + c);
    acc += wv.x * xx.x + wv.y * xx.y + wv.z * xx.z + wv.w * xx.w;
  }
#pragma unroll
  for (int off = 32; off; off >>= 1) acc += __shfl_xor(acc, off, 64);
  return acc;
}

// per-block redundant LayerNorm: o = LN(x1+x2)*g+b, o in LDS (256 threads)
__device__ void block_ln(const float* x1, const float* x2,
                         const float* __restrict__ g, const float* __restrict__ be,
                         float* o, float* red) {
  int tid = threadIdx.x;
  float loc[8]; float s = 0.f;
#pragma unroll
  for (int j = 0; j < 8; ++j) { int i = tid * 8 + j; float v = x1[i] + x2[i]; loc[j] = v; s += v; }
#pragma unroll
  for (int off = 32; off; off >>= 1) s += __shfl_xor(s, off, 64);
  __syncthreads();
  if ((tid & 63) == 0) red[tid >> 6] = s;
  __syncthreads();
  float m = (red[0] + red[1] + red[2] + red[3]) * (1.f / 2048.f);
  s = 0.f;
#pragma unroll
  for (int j = 0; j < 8; ++j) { float d = loc[j] - m; s += d * d; }
#pragma unroll
  for (int off = 32; off; off >>= 1) s += __shfl_xor(s, off, 64);
  __syncthreads();
  if ((tid & 63) == 0) red[tid >> 6] = s;
  __syncthreads();
  float inv = 1.f / sqrtf((red[0] + red[1] + red[2] + red[3]) * (1.f / 2048.f) + EPSV);
#pragma unroll
  for (int j = 0; j < 8; ++j) { int i = tid * 8 + j; o[i] = (loc[j] - m) * inv * g[i] + be[i]; }
  __syncthreads();
}

__global__ void init_kernel(const float* __restrict__ w0, float* __restrict__ state,
                            float* __restrict__ acc, float* __restrict__ scal) {
  int i = blockIdx.x * 256 + threadIdx.x;
  if (i < DD) { state[i] = w0[i]; acc[i] = 0.f; }
  if (i == 0) { scal[0] = 0.f; scal[1] = 1.f; }
}

// one-time: wm fp32 -> wmb (row-major bf16) + wmbT (transposed bf16)
__global__ void prep_wm(const float* __restrict__ wm, unsigned short* __restrict__ wmb,
                        unsigned short* __restrict__ wmbT) {
  __shared__ unsigned short tile[64][72];
  int bk = blockIdx.x & 127, bc = blockIdx.x >> 7;
  int k0 = bk * 64, c0 = bc * 64;
  int tx = threadIdx.x & 15, ty = threadIdx.x >> 4;
#pragma unroll
  for (int rr = 0; rr < 4; ++rr) {
    int r = ty + rr * 16;
    float4 v = *reinterpret_cast<const float4*>(wm + (size_t)(k0 + r) * DD + c0 + tx * 4);
    ushort4 u4;
    u4.x = f2bf(v.x); u4.y = f2bf(v.y); u4.z = f2bf(v.z); u4.w = f2bf(v.w);
    *reinterpret_cast<ushort4*>(wmb + (size_t)(k0 + r) * DD + c0 + tx * 4) = u4;
    tile[tx * 4 + 0][r] = u4.x; tile[tx * 4 + 1][r] = u4.y;
    tile[tx * 4 + 2][r] = u4.z; tile[tx * 4 + 3][r] = u4.w;
  }
  __syncthreads();
#pragma unroll
  for (int rr = 0; rr < 4; ++rr) {
    int c = ty + rr * 16;
    ushort4 o;
    o.x = tile[c][tx * 4]; o.y = tile[c][tx * 4 + 1];
    o.z = tile[c][tx * 4 + 2]; o.w = tile[c][tx * 4 + 3];
    *reinterpret_cast<ushort4*>(wmbT + (size_t)(c0 + c) * NK + k0 + tx * 4) = o;
  }
}

// y[r] = act( dot(W[row,:C], x) + bias[r] ), wave per row
__global__ void matvec_kernel(const float* __restrict__ W, const float* __restrict__ bias,
                              const float* __restrict__ x, float* __restrict__ y,
                              int R, int C, int act, int perhead,
                              const float* __restrict__ scal, int gated) {
  if (gated && scal[1] == 0.f) return;
  int wid = threadIdx.x >> 6, lane = threadIdx.x & 63;
  int row = blockIdx.x * 4 + wid;
  if (row >= R) return;
  const float* w = W + (size_t)row * C;
  const float* xv = perhead ? (x + (size_t)(row >> 7) * C) : x;
  float acc = 0.f;
  for (int c = lane * 4; c < C; c += 256) {
    float4 wv = *reinterpret_cast<const float4*>(w + c);
    float4 xx = *reinterpret_cast<const float4*>(xv + c);
    acc += wv.x * xx.x + wv.y * xx.y + wv.z * xx.z + wv.w * xx.w;
  }
  for (int off = 32; off > 0; off >>= 1) acc += __shfl_xor(acc, off, 64);
  if (lane == 0) {
    float r = acc + bias[row];
    if (act == 1) r = gelu_exact(r);
    y[row] = r;
  }
}

// t[h][c] = sum_d q[h*128+d] * Wk[h*128+d][c]
__global__ void tproj_kernel(const float* __restrict__ Wk, const float* __restrict__ q,
                             float* __restrict__ t, unsigned short* __restrict__ tb,
                             int obf, const float* __restrict__ scal) {
  if (scal[1] == 0.f) return;
  int h = blockIdx.x >> 4, ct = blockIdx.x & 15;
  int c = ct * 128 + threadIdx.x;
  const float* wb = Wk + (size_t)(h * HDIM) * DD + c;
  const float* qh = q + h * HDIM;
  float acc = 0.f;
  for (int d = 0; d < HDIM; ++d) acc += qh[d] * wb[(size_t)d * DD];
  if (obf) tb[h * DD + c] = f2bf(acc);
  else     t[h * DD + c] = acc;
}

// part_s[cc][h][r] = sum_{c in 256-chunk cc} wm[r][c]*t[h][c] (MFMA, verified R4)
__global__ __launch_bounds__(256, 4) void scores_mfma(const unsigned short* __restrict__ wmb,
                                                      const unsigned short* __restrict__ tb,
                                                      float* __restrict__ part_s,
                                                      const float* __restrict__ scal) {
  if (scal[1] == 0.f) return;
  int w = threadIdx.x >> 6, lane = threadIdx.x & 63;
  int task = blockIdx.x * 4 + w;
  int cc = task & 7, rg = task >> 3;
  int r0 = rg * 16, c0 = cc * 256;
  int l15 = lane & 15, kg = lane >> 4;
  const unsigned short* ap = wmb + (size_t)(r0 + l15) * DD + c0 + kg * 8;
  const unsigned short* bp = tb + (size_t)l15 * DD + c0 + kg * 8;
  bf16x8 a[8], b[8];
#pragma unroll
  for (int i = 0; i < 8; ++i) {
    a[i] = *reinterpret_cast<const bf16x8*>(ap + i * 32);
    b[i] = *reinterpret_cast<const bf16x8*>(bp + i * 32);
  }
  f32x4 acc = {0.f, 0.f, 0.f, 0.f};
#pragma unroll
  for (int i = 0; i < 8; ++i)
    acc = __builtin_amdgcn_mfma_f32_16x16x32_bf16(a[i], b[i], acc, 0, 0, 0);
  float* op = part_s + ((size_t)cc * NH + l15) * NK + r0 + kg * 4;
#pragma unroll
  for (int r = 0; r < 4; ++r) op[r] = acc[r];
}

// part_u[kc][h][c] = sum_{k in 512-chunk kc} p[h][k]*wm[k][c] (MFMA, verified R4)
__global__ __launch_bounds__(256, 4) void u_mfma(const unsigned short* __restrict__ wmbT,
                                                 const unsigned short* __restrict__ pb,
                                                 float* __restrict__ part_u,
                                                 const float* __restrict__ scal) {
  if (scal[1] == 0.f) return;
  int w = threadIdx.x >> 6, lane = threadIdx.x & 63;
  int task = blockIdx.x * 4 + w;
  int ct = task & 127, kc = task >> 7;
  int c0 = ct * 16, k0 = kc * 512;
  int l15 = lane & 15, kg = lane >> 4;
  const unsigned short* ap = pb + (size_t)l15 * NK + k0 + kg * 8;
  const unsigned short* bp = wmbT + (size_t)(c0 + l15) * NK + k0 + kg * 8;
  f32x4 acc = {0.f, 0.f, 0.f, 0.f};
#pragma unroll
  for (int half = 0; half < 2; ++half) {
    bf16x8 a[8], b[8];
#pragma unroll
    for (int i = 0; i < 8; ++i) {
      a[i] = *reinterpret_cast<const bf16x8*>(ap + half * 256 + i * 32);
      b[i] = *reinterpret_cast<const bf16x8*>(bp + half * 256 + i * 32);
    }
#pragma unroll
    for (int i = 0; i < 8; ++i)
      acc = __builtin_amdgcn_mfma_f32_16x16x32_bf16(a[i], b[i], acc, 0, 0, 0);
  }
  float* op = part_u + ((size_t)kc * NH + kg * 4) * DD + c0 + l15;
#pragma unroll
  for (int r = 0; r < 4; ++r) op[(size_t)r * DD] = acc[r];
}

// per-head softmax over 8192; sums 8 partials, scale 1/sqrt(128); fp32 or bf16 out
__global__ void softmax_kernel(const float* __restrict__ part_s, float* __restrict__ p,
                               unsigned short* __restrict__ pb, int obf,
                               const float* __restrict__ scal) {
  if (scal[1] == 0.f) return;
  int h = blockIdx.x, tid = threadIdx.x;
  __shared__ float red[256];
  float v[32]; float mx = -1e30f;
  for (int j = 0; j < 32; ++j) {
    int k = tid + j * 256; float s = 0.f;
    for (int cc = 0; cc < 8; ++cc) s += part_s[((size_t)cc * NH + h) * NK + k];
    s *= 0.08838834764831845f;
    v[j] = s; mx = fmaxf(mx, s);
  }
  red[tid] = mx; __syncthreads();
  for (int off = 128; off > 0; off >>= 1) { if (tid < off) red[tid] = fmaxf(red[tid], red[tid + off]); __syncthreads(); }
  mx = red[0]; __syncthreads();
  float sum = 0.f;
  for (int j = 0; j < 32; ++j) { v[j] = expf(v[j] - mx); sum += v[j]; }
  red[tid] = sum; __syncthreads();
  for (int off = 128; off > 0; off >>= 1) { if (tid < off) red[tid] += red[tid + off]; __syncthreads(); }
  float inv = 1.f / red[0];
  for (int j = 0; j < 32; ++j) {
    float val = v[j] * inv;
    size_t idx = (size_t)h * NK + tid + j * 256;
    if (obf) pb[idx] = f2bf(val);
    else     p[idx] = val;
  }
}

// fused: uh = sum_kc part_u[kc][h][:] (LDS) ; O[row] = Wv[row,:] . uh + bv[row]
// grid 512 = 16 heads x 32 row-groups of 4
__global__ __launch_bounds__(256) void o_fused_kernel(const float* __restrict__ part_u,
                                                      const float* __restrict__ Wv,
                                                      const float* __restrict__ bv,
                                                      float* __restrict__ O,
                                                      const float* __restrict__ scal) {
  if (scal[1] == 0.f) return;
  __shared__ float uh[2048];
  int tid = threadIdx.x, wid = tid >> 6, lane = tid & 63;
  int h = blockIdx.x >> 5;
#pragma unroll
  for (int j = 0; j < 8; ++j) {
    int c = tid + j * 256;
    float ss = 0.f;
#pragma unroll
    for (int kc = 0; kc < 16; ++kc) ss += part_u[((size_t)kc * NH + h) * DD + c];
    uh[c] = ss;
  }
  __syncthreads();
  int row = h * HDIM + (blockIdx.x & 31) * 4 + wid;
  float a = wave_dot(Wv + (size_t)row * DD, uh, DD);
  if (lane == 0) O[row] = a + bv[row];
}

// fused: s1 = LN1(state+cross) per block ; V[row] = Wv_self[row,:] . s1 + bv
__global__ __launch_bounds__(256) void v_ln1_kernel(const float* __restrict__ ST,
                                                    const float* __restrict__ CR,
                                                    const float* __restrict__ g1,
                                                    const float* __restrict__ b1,
                                                    const float* __restrict__ W,
                                                    const float* __restrict__ bias,
                                                    float* __restrict__ V,
                                                    const float* __restrict__ scal) {
  if (scal[1] == 0.f) return;
  __shared__ float s1[2048];
  __shared__ float red[8];
  block_ln(ST, CR, g1, b1, s1, red);
  int wid = threadIdx.x >> 6, lane = threadIdx.x & 63;
  int row = blockIdx.x * 4 + wid;
  float a = wave_dot(W + (size_t)row * DD, s1, DD);
  if (lane == 0) V[row] = a + bias[row];
}

// fused: s1 = LN1(state+cross); s2 = LN2(s1+sa); H1 = gelu(ffn_w1 @ s2 + b)
// grid 512, 4 rows/wave
__global__ __launch_bounds__(256) void ffn1_kernel(const float* __restrict__ ST,
                                                   const float* __restrict__ CR,
                                                   const float* __restrict__ SA,
                                                   const float* __restrict__ g1,
                                                   const float* __restrict__ b1,
                                                   const float* __restrict__ g2,
                                                   const float* __restrict__ b2,
                                                   const float* __restrict__ W,
                                                   const float* __restrict__ bias,
                                                   float* __restrict__ H1,
                                                   const float* __restrict__ scal) {
  if (scal[1] == 0.f) return;
  __shared__ float s1[2048];
  __shared__ float s2[2048];
  __shared__ float red[8];
  block_ln(ST, CR, g1, b1, s1, red);
  block_ln(s1, SA, g2, b2, s2, red);
  int wid = threadIdx.x >> 6, lane = threadIdx.x & 63;
  int gw = blockIdx.x * 4 + wid;
  for (int r = gw; r < NFFN; r += 2048) {
    float a = wave_dot(W + (size_t)r * DD, s2, DD);
    if (lane == 0) H1[r] = gelu_exact(a + bias[r]);
  }
}

// fused: ns = LN3(LN2(LN1(st+cr)+sa)+f2); halting head; ACT update (1 block)
__global__ void act_ln3_kernel(const float* __restrict__ ST, const float* __restrict__ CR,
                               const float* __restrict__ SA, const float* __restrict__ F2,
                               const float* __restrict__ g1, const float* __restrict__ b1,
                               const float* __restrict__ g2, const float* __restrict__ b2,
                               const float* __restrict__ g3, const float* __restrict__ b3,
                               const float* __restrict__ hw1, const float* __restrict__ hb1,
                               const float* __restrict__ hw2, const float* __restrict__ hb2,
                               float* __restrict__ state, float* __restrict__ acc,
                               float* __restrict__ scal, const int* __restrict__ max_steps,
                               int step) {
  if (step >= max_steps[0]) return;
  if (scal[1] == 0.f) return;
  __shared__ float sA[2048];
  __shared__ float sB[2048];
  __shared__ float red[8];
  __shared__ float hh[NHID];
  __shared__ float wbc;
  int tid = threadIdx.x;
  block_ln(ST, CR, g1, b1, sA, red);   // sA = s1
  block_ln(sA, SA, g2, b2, sB, red);   // sB = s2
  block_ln(sB, F2, g3, b3, sA, red);   // sA = ns (sB free after this returns)
  int row = tid >> 3, seg = tid & 7;
  const float* wr = hw1 + (size_t)row * DD + seg * 256;
  const float* np = sA + seg * 256;
  float s = 0.f;
  for (int i = 0; i < 256; ++i) s += wr[i] * np[i];
  sB[row * 8 + seg] = s;
  __syncthreads();
  if (tid < NHID) {
    float t2 = hb1[tid];
#pragma unroll
    for (int j = 0; j < 8; ++j) t2 += sB[tid * 8 + j];
    hh[tid] = gelu_exact(t2);
  }
  __syncthreads();
  if (tid == 0) {
    float hs = hb2[0];
    for (int j = 0; j < NHID; ++j) hs += hh[j] * hw2[j];
    float halt = 1.f / (1.f + expf(-hs));
    float cum = scal[0];
    float ncum = cum + halt;
    int halts = (ncum >= 1.f - 1e-6f);
    wbc = halts ? (1.f - cum) : halt;
    scal[0] = ncum;
    scal[1] = halts ? 0.f : 1.f;
  }
  __syncthreads();
  float w = wbc;
  for (int i = tid; i < DD; i += 256) { acc[i] += w * sA[i]; state[i] = sA[i]; }
}

__global__ void final_kernel(const float* __restrict__ state, const float* __restrict__ acc,
                             const float* __restrict__ scal, float* __restrict__ out) {
  float cum = scal[0];
  float w = (cum < 1.f - 1e-6f) ? (1.f - cum) : 0.f;
  int i = blockIdx.x * 256 + threadIdx.x;
  if (i < DD) out[i] = acc[i] + w * state[i];
}

// ================= tier B fallback (fp32 multi-kernel, verified R4) =================

#define FMA16(wvv, tp)                                                       \
  {                                                                          \
    float4 t0 = tp[0], t1 = tp[1], t2 = tp[2], t3 = tp[3];                   \
    acc[0] += wvv * t0.x; acc[1] += wvv * t0.y;                              \
    acc[2] += wvv * t0.z; acc[3] += wvv * t0.w;                              \
    acc[4] += wvv * t1.x; acc[5] += wvv * t1.y;                              \
    acc[6] += wvv * t1.z; acc[7] += wvv * t1.w;                              \
    acc[8] += wvv * t2.x; acc[9] += wvv * t2.y;                              \
    acc[10] += wvv * t2.z; acc[11] += wvv * t2.w;                            \
    acc[12] += wvv * t3.x; acc[13] += wvv * t3.y;                            \
    acc[14] += wvv * t3.z; acc[15] += wvv * t3.w;                            \
  }

__global__ void scores_kernel(const float* __restrict__ wm, const float* __restrict__ t,
                              float* __restrict__ part_s, const float* __restrict__ scal) {
  if (scal[1] == 0.f) return;
  int kt = blockIdx.x >> 3, cc = blockIdx.x & 7;
  int tid = threadIdx.x;
  int k0 = kt * 128, c0 = cc * 256;
  __shared__ float wlds[128 * 33];
  __shared__ float tlds[256 * 20];
  for (int j = 0; j < 32; ++j) {
    int idx = j * 128 + tid;
    int h = idx >> 8, c = idx & 255;
    tlds[c * 20 + h] = t[(size_t)h * DD + c0 + c];
  }
  float acc[NH];
#pragma unroll
  for (int h = 0; h < NH; ++h) acc[h] = 0.f;
  for (int sl = 0; sl < 8; ++sl) {
    int cbase = c0 + sl * 32;
    __syncthreads();
    for (int p = 0; p < 8; ++p) {
      int f = p * 128 + tid;
      int r = f >> 3, fc = f & 7;
      float4 v = *reinterpret_cast<const float4*>(wm + (size_t)(k0 + r) * DD + cbase + fc * 4);
      float* d = wlds + r * 33 + fc * 4;
      d[0] = v.x; d[1] = v.y; d[2] = v.z; d[3] = v.w;
    }
    __syncthreads();
    const float* myrow = wlds + tid * 33;
#pragma unroll 4
    for (int cb = 0; cb < 32; ++cb) {
      float wvv = myrow[cb];
      const float4* tp = reinterpret_cast<const float4*>(tlds + (size_t)(sl * 32 + cb) * 20);
      FMA16(wvv, tp);
    }
  }
#pragma unroll
  for (int h = 0; h < NH; ++h)
    part_s[((size_t)cc * NH + h) * NK + k0 + tid] = acc[h];
}

#define U1FMA(i, ph) \
  acc[i].x += w4.x * (ph); acc[i].y += w4.y * (ph); \
  acc[i].z += w4.z * (ph); acc[i].w += w4.w * (ph);

template <int KCH>
__global__ void u1_kernel(const float* __restrict__ wm, const float* __restrict__ p,
                          float* __restrict__ part_u, const float* __restrict__ scal) {
  if (scal[1] == 0.f) return;
  int kc = blockIdx.x >> 2, ct = blockIdx.x & 3;
  int tid = threadIdx.x;
  int k0 = kc * KCH;
  int c = ct * 512 + tid * 4;
  __shared__ float plds[KCH * 16];
  for (int j = 0; j < KCH * 16 / 128; ++j) {
    int idx = j * 128 + tid;
    int h = idx / KCH, k = idx % KCH;
    plds[k * 16 + h] = p[(size_t)h * NK + k0 + k];
  }
  __syncthreads();
  float4 acc[NH];
#pragma unroll
  for (int h = 0; h < NH; ++h) acc[h] = make_float4(0.f, 0.f, 0.f, 0.f);
#pragma unroll 2
  for (int k = 0; k < KCH; ++k) {
    float4 w4 = *reinterpret_cast<const float4*>(wm + (size_t)(k0 + k) * DD + c);
    const float4* pp = reinterpret_cast<const float4*>(plds + k * 16);
    float4 p0 = pp[0], p1 = pp[1], p2 = pp[2], p3 = pp[3];
    U1FMA(0, p0.x)  U1FMA(1, p0.y)  U1FMA(2, p0.z)  U1FMA(3, p0.w)
    U1FMA(4, p1.x)  U1FMA(5, p1.y)  U1FMA(6, p1.z)  U1FMA(7, p1.w)
    U1FMA(8, p2.x)  U1FMA(9, p2.y)  U1FMA(10, p2.z) U1FMA(11, p2.w)
    U1FMA(12, p3.x) U1FMA(13, p3.y) U1FMA(14, p3.z) U1FMA(15, p3.w)
  }
#pragma unroll
  for (int h = 0; h < NH; ++h)
    *reinterpret_cast<float4*>(part_u + ((size_t)kc * NH + h) * DD + c) = acc[h];
}

__global__ void u2_kernel(const float* __restrict__ part_u, float* __restrict__ u,
                          const float* __restrict__ scal, int nkc) {
  if (scal[1] == 0.f) return;
  int i = blockIdx.x * 256 + threadIdx.x;
  float s = 0.f;
  for (int kc = 0; kc < nkc; ++kc) s += part_u[(size_t)kc * NH * DD + i];
  u[i] = s;
}

__global__ void ln_kernel(const float* __restrict__ a, const float* __restrict__ r,
                          const float* __restrict__ g, const float* __restrict__ beta,
                          float* __restrict__ out, const float* __restrict__ scal) {
  if (scal[1] == 0.f) return;
  __shared__ float red[256];
  __shared__ float mv[2];
  int tid = threadIdx.x;
  float x[8]; float s = 0.f;
  for (int j = 0; j < 8; ++j) { int i = tid * 8 + j; x[j] = a[i] + r[i]; s += x[j]; }
  red[tid] = s; __syncthreads();
  for (int off = 128; off > 0; off >>= 1) { if (tid < off) red[tid] += red[tid + off]; __syncthreads(); }
  if (tid == 0) mv[0] = red[0] * (1.f / DD);
  __syncthreads();
  float m = mv[0]; s = 0.f;
  for (int j = 0; j < 8; ++j) { float d = x[j] - m; s += d * d; }
  red[tid] = s; __syncthreads();
  for (int off = 128; off > 0; off >>= 1) { if (tid < off) red[tid] += red[tid + off]; __syncthreads(); }
  if (tid == 0) mv[1] = 1.f / sqrtf(red[0] * (1.f / DD) + EPSV);
  __syncthreads();
  float inv = mv[1];
  for (int j = 0; j < 8; ++j) { int i = tid * 8 + j; out[i] = (x[j] - m) * inv * g[i] + beta[i]; }
}

__global__ void act_kernel(const float* __restrict__ hw1, const float* __restrict__ hb1,
                           const float* __restrict__ hw2, const float* __restrict__ hb2,
                           const float* __restrict__ ns, float* __restrict__ state,
                           float* __restrict__ acc, float* __restrict__ scal,
                           const int* __restrict__ max_steps, int step) {
  if (step >= max_steps[0]) return;
  if (scal[1] == 0.f) return;
  __shared__ float red[NHID][9];
  __shared__ float hh[NHID];
  __shared__ float wbc;
  int tid = threadIdx.x;
  int row = tid >> 3, seg = tid & 7;
  const float* wr = hw1 + (size_t)row * DD + seg * 256;
  const float* nsp = ns + seg * 256;
  float s = 0.f;
  for (int i = 0; i < 256; ++i) s += wr[i] * nsp[i];
  red[row][seg] = s; __syncthreads();
  if (tid < NHID) {
    float t = hb1[tid];
    for (int j = 0; j < 8; ++j) t += red[tid][j];
    hh[tid] = gelu_exact(t);
  }
  __syncthreads();
  if (tid == 0) {
    float hs = hb2[0];
    for (int j = 0; j < NHID; ++j) hs += hh[j] * hw2[j];
    float halt = 1.f / (1.f + expf(-hs));
    float cum = scal[0];
    float ncum = cum + halt;
    int halts = (ncum >= 1.f - 1e-6f);
    wbc = halts ? (1.f - cum) : halt;
    scal[0] = ncum;
    scal[1] = halts ? 0.f : 1.f;
  }
  __syncthreads();
  float w = wbc;
  for (int i = tid; i < DD; i += 256) { acc[i] += w * ns[i]; state[i] = ns[i]; }
}

extern "C" void kernel_launch(void* const* d_in, const int* in_sizes, int n_in,
                              void* d_out, int out_size, void* d_ws, size_t ws_size,
                              hipStream_t stream) {
  const float* workspace   = (const float*)d_in[0];
  const float* wm          = (const float*)d_in[1];
  const float* self_in_w   = (const float*)d_in[2];
  const float* self_in_b   = (const float*)d_in[3];
  const float* self_out_w  = (const float*)d_in[4];
  const float* self_out_b  = (const float*)d_in[5];
  const float* cross_in_w  = (const float*)d_in[6];
  const float* cross_in_b  = (const float*)d_in[7];
  const float* cross_out_w = (const float*)d_in[8];
  const float* cross_out_b = (const float*)d_in[9];
  const float* ffn_w1      = (const float*)d_in[10];
  const float* ffn_b1      = (const float*)d_in[11];
  const float* ffn_w2      = (const float*)d_in[12];
  const float* ffn_b2      = (const float*)d_in[13];
  const float* ln1_g = (const float*)d_in[14];
  const float* ln1_b = (const float*)d_in[15];
  const float* ln2_g = (const float*)d_in[16];
  const float* ln2_b = (const float*)d_in[17];
  const float* ln3_g = (const float*)d_in[18];
  const float* ln3_b = (const float*)d_in[19];
  const float* halt_w1 = (const float*)d_in[20];
  const float* halt_b1 = (const float*)d_in[21];
  const float* halt_w2 = (const float*)d_in[22];
  const float* halt_b2 = (const float*)d_in[23];
  const int*   max_steps = (const int*)d_in[24];

  float* ws = (float*)d_ws;
  float* out = (float*)d_out;

  float* ST = ws + W_ST;  float* AC = ws + W_AC;  float* SC = ws + W_SC;
  float* Q_ = ws + W_Q;   float* PS = ws + W_PS;  float* O_ = ws + W_O;
  float* CR = ws + W_CR;  float* V_ = ws + W_V;   float* SA = ws + W_SA;
  float* H1 = ws + W_H1;  float* F2 = ws + W_F2;  float* PU = ws + W_PUA;
  unsigned short* TB  = (unsigned short*)(ws + W_TB);
  unsigned short* PB  = (unsigned short*)(ws + W_PB);
  unsigned short* WMB = (unsigned short*)(ws + W_WMB);
  unsigned short* WMT = (unsigned short*)(ws + W_WMT);

  const bool tierA = W_ENDA * sizeof(float) <= ws_size;

  init_kernel<<<8, 256, 0, stream>>>(workspace, ST, AC, SC);

  if (tierA) {
    prep_wm<<<4096, 256, 0, stream>>>(wm, WMB, WMT);
    for (int s = 0; s < 5; ++s) {
      // cross-attention (factorized; K/V never materialized)
      matvec_kernel<<<512, 256, 0, stream>>>(cross_in_w, cross_in_b, ST, Q_, DD, DD, 0, 0, SC, 1);
      tproj_kernel<<<256, 128, 0, stream>>>(cross_in_w + (size_t)DD * DD, Q_, nullptr, TB, 1, SC);
      scores_mfma<<<1024, 256, 0, stream>>>(WMB, TB, PS, SC);
      softmax_kernel<<<16, 256, 0, stream>>>(PS, nullptr, PB, 1, SC);
      u_mfma<<<512, 256, 0, stream>>>(WMT, PB, PU, SC);
      o_fused_kernel<<<512, 256, 0, stream>>>(PU, cross_in_w + (size_t)2 * DD * DD,
                                              cross_in_b + 2 * DD, O_, SC);
      matvec_kernel<<<512, 256, 0, stream>>>(cross_out_w, cross_out_b, O_, CR, DD, DD, 0, 0, SC, 1);
      // self-attn over 1 token (softmax==1): v then out-proj, ln1 fused into v
      v_ln1_kernel<<<512, 256, 0, stream>>>(ST, CR, ln1_g, ln1_b,
                                            self_in_w + (size_t)2 * DD * DD,
                                            self_in_b + 2 * DD, V_, SC);
      matvec_kernel<<<512, 256, 0, stream>>>(self_out_w, self_out_b, V_, SA, DD, DD, 0, 0, SC, 1);
      // FFN (ln1+ln2 recomputed per block)
      ffn1_kernel<<<512, 256, 0, stream>>>(ST, CR, SA, ln1_g, ln1_b, ln2_g, ln2_b,
                                           ffn_w1, ffn_b1, H1, SC);
      matvec_kernel<<<512, 256, 0, stream>>>(ffn_w2, ffn_b2, H1, F2, DD, NFFN, 0, 0, SC, 1);
      // ln3 + halting head + ACT update
      act_ln3_kernel<<<1, 256, 0, stream>>>(ST, CR, SA, F2, ln1_g, ln1_b, ln2_g, ln2_b,
                                            ln3_g, ln3_b, halt_w1, halt_b1, halt_w2, halt_b2,
                                            ST, AC, SC, max_steps, s);
    }
  } else {
    float* T_ = ws + W_T;   float* P_ = ws + W_P;   float* U_ = ws + W_U;
    float* S1 = ws + W_S1;  float* S2 = ws + W_S2;  float* NS = ws + W_NS;
    float* PUB = ws + W_PUB;
    const bool bigB = W_ENDB * sizeof(float) <= ws_size;
    for (int s = 0; s < 5; ++s) {
      matvec_kernel<<<512, 256, 0, stream>>>(cross_in_w, cross_in_b, ST, Q_, DD, DD, 0, 0, SC, 1);
      tproj_kernel<<<256, 128, 0, stream>>>(cross_in_w + (size_t)DD * DD, Q_, T_, nullptr, 0, SC);
      scores_kernel<<<512, 128, 0, stream>>>(wm, T_, PS, SC);
      softmax_kernel<<<16, 256, 0, stream>>>(PS, P_, nullptr, 0, SC);
      if (bigB) u1_kernel<64><<<512, 128, 0, stream>>>(wm, P_, PUB, SC);
      else      u1_kernel<256><<<128, 128, 0, stream>>>(wm, P_, PUB, SC);
      u2_kernel<<<128, 256, 0, stream>>>(PUB, U_, SC, bigB ? 128 : 32);
      matvec_kernel<<<512, 256, 0, stream>>>(cross_in_w + (size_t)2 * DD * DD, cross_in_b + 2 * DD,
                                             U_, O_, DD, DD, 0, 1, SC, 1);
      matvec_kernel<<<512, 256, 0, stream>>>(cross_out_w, cross_out_b, O_, CR, DD, DD, 0, 0, SC, 1);
      ln_kernel<<<1, 256, 0, stream>>>(ST, CR, ln1_g, ln1_b, S1, SC);
      matvec_kernel<<<512, 256, 0, stream>>>(self_in_w + (size_t)2 * DD * DD, self_in_b + 2 * DD,
                                             S1, V_, DD, DD, 0, 0, SC, 1);
      matvec_kernel<<<512, 256, 0, stream>>>(self_out_w, self_out_b, V_, SA, DD, DD, 0, 0, SC, 1);
      ln_kernel<<<1, 256, 0, stream>>>(S1, SA, ln2_g, ln2_b, S2, SC);
      matvec_kernel<<<2048, 256, 0, stream>>>(ffn_w1, ffn_b1, S2, H1, NFFN, DD, 1, 0, SC, 1);
      matvec_kernel<<<512, 256, 0, stream>>>(ffn_w2, ffn_b2, H1, F2, DD, NFFN, 0, 0, SC, 1);
      ln_kernel<<<1, 256, 0, stream>>>(S2, F2, ln3_g, ln3_b, NS, SC);
      act_kernel<<<1, 256, 0, stream>>>(halt_w1, halt_b1, halt_w2, halt_b2, NS, ST, AC, SC,
                                        max_steps, s);
    }
  }
  final_kernel<<<8, 256, 0, stream>>>(ST, AC, SC, out);
}